// Round 4
// baseline (258.848 us; speedup 1.0000x reference)
//
#include <hip/hip_runtime.h>

// Causal self-attention fwd: x(4,2048,1024)fp32, W_qkv(1024,3072), W_proj(1024,1024)
// Pipeline: [transpose W->bf16] [x->bf16] [GEMM1 qkv + fused V-transpose] [RoPE q,k]
//           [flash attn] [GEMM2 out]
// R5: attn 32q/wave, paired Q-tiles, exp2 shift-free softmax.
// R6: swapped QK^T + in-register P via cvt_pk_bf16 + permlane swaps (no P LDS).
// R8: GEMM1 K-granule pipeline, BM=128 BN=384 BK=64, 512 blocks = 2 full rounds.
// R9: fix R8's fatal phase-count bug: K=1024 -> 32 phases (16 kt x 2 ks), not 64.
//     R8 indexed kt to 31 (K=2048) -> global_load_lds read ~2KB past the 72MiB
//     workspace (xb is the last region) -> GPU page fault -> container abort.
//     Ledger (32 granules): prologue stages g0-g2, drain to 8; phase ph stages
//     g(ph+3) into region (ph+3)&3 (last read at ph-1, lgkm-drained+barriered);
//     vmcnt(8) steady (2 granules in flight, never 0); tail drains 8->4->0.

#define BATCH 4
#define SEQ   2048
#define DM    1024
#define NH    16
#define HD    64
#define QKV_W 3072

typedef short bf16x8 __attribute__((ext_vector_type(8)));
typedef float f32x4  __attribute__((ext_vector_type(4)));
typedef unsigned u32x4 __attribute__((ext_vector_type(4)));
typedef unsigned short bf16_t;

__device__ __forceinline__ unsigned short f2bf(float f) {
  unsigned u = __float_as_uint(f);
  u += 0x7fffu + ((u >> 16) & 1u);   // round-to-nearest-even
  return (unsigned short)(u >> 16);
}
__device__ __forceinline__ float bf2f(unsigned short s) {
  return __uint_as_float((unsigned)s << 16);
}
// async global->LDS, 16B per lane; LDS dest is wave-uniform base + lane*16
__device__ __forceinline__ void gld16(const void* g, void* l) {
  __builtin_amdgcn_global_load_lds(
      (const __attribute__((address_space(1))) unsigned int*)g,
      (__attribute__((address_space(3))) unsigned int*)l, 16, 0, 0);
}
// packed f32x2 -> bf16x2 (RTNE), lo=a hi=b
__device__ __forceinline__ unsigned cvt_pk_bf16(float a, float b) {
  unsigned r;
  asm("v_cvt_pk_bf16_f32 %0, %1, %2" : "=v"(r) : "v"(a), "v"(b));
  return r;
}
// a.rows{2,3} <-> b.rows{0,1}  (rows = 16-lane groups)
__device__ __forceinline__ void permlane32_swap(unsigned& a, unsigned& b) {
  asm("v_permlane32_swap_b32 %0, %1" : "+v"(a), "+v"(b));
}
// a.rows{1,3} <-> b.rows{0,2}
__device__ __forceinline__ void permlane16_swap(unsigned& a, unsigned& b) {
  asm("v_permlane16_swap_b32 %0, %1" : "+v"(a), "+v"(b));
}

// ---------------- W[K][N] fp32 -> Wt[N][K] bf16 ----------------
__global__ __launch_bounds__(256) void k_transpose(const float* __restrict__ W,
                                                   bf16_t* __restrict__ Wt,
                                                   int K, int N) {
  __shared__ float tile[32][33];
  const int tx = threadIdx.x, ty = threadIdx.y;   // (32,8)
  const int n0 = blockIdx.x * 32, k0 = blockIdx.y * 32;
#pragma unroll
  for (int j = 0; j < 4; ++j)
    tile[ty + j * 8][tx] = W[(size_t)(k0 + ty + j * 8) * N + n0 + tx];
  __syncthreads();
#pragma unroll
  for (int j = 0; j < 4; ++j)
    Wt[(size_t)(n0 + ty + j * 8) * K + k0 + tx] = f2bf(tile[tx][ty + j * 8]);
}

// ---------------- fp32 -> bf16 elementwise ----------------
__global__ __launch_bounds__(256) void k_cvt(const float* __restrict__ x,
                                             bf16_t* __restrict__ xb) {
  const int i = (blockIdx.x * 256 + threadIdx.x) * 4;
  float4 v = *(const float4*)(x + i);
  unsigned lo = (unsigned)f2bf(v.x) | ((unsigned)f2bf(v.y) << 16);
  unsigned hi = (unsigned)f2bf(v.z) | ((unsigned)f2bf(v.w) << 16);
  *(uint2*)(xb + i) = make_uint2(lo, hi);
}

// ---------------- RoPE in place on q,k sections of qkv ----------------
__global__ __launch_bounds__(256) void k_rope(bf16_t* __restrict__ qkv) {
  const int t = blockIdx.x * 256 + threadIdx.x;
  const int i = t & 31;            // freq index 0..31
  const int h = (t >> 5) & 15;     // head
  const int s = (t >> 9) & 2047;   // position
  const int b = t >> 20;
  const float inv = __expf((float)i * -0.28782313662425575f); // -ln(10000)/32
  float sn, cs;
  sincosf((float)s * inv, &sn, &cs);
  size_t base = ((size_t)(b * SEQ + s)) * QKV_W + h * HD + 2 * i;
#pragma unroll
  for (int part = 0; part < 2; ++part) {      // q then k
    unsigned u = *(unsigned*)(qkv + base + part * DM);
    float e = bf2f((unsigned short)(u & 0xffffu));
    float o = bf2f((unsigned short)(u >> 16));
    unsigned short e2 = f2bf(e * cs - o * sn);
    unsigned short o2 = f2bf(e * sn + o * cs);
    *(unsigned*)(qkv + base + part * DM) = (unsigned)e2 | ((unsigned)o2 << 16);
  }
}

// ---------------- 128x128 bf16 GEMM (2-phase) — used for GEMM2 ----------------
template<int MODE>
__global__ __launch_bounds__(256) void k_gemm(const bf16_t* __restrict__ A,
                                              const bf16_t* __restrict__ Bt,
                                              void* __restrict__ Cout,
                                              bf16_t* __restrict__ vt,
                                              int M, int N, int K) {
  __shared__ __align__(16) short As[128 * 64];
  __shared__ __align__(16) short Bs[128 * 64];
  const int tid = threadIdx.x;
  const int wave = tid >> 6, lane = tid & 63;
  const int quad = lane >> 4, l16 = lane & 15;
  const int wm = (wave >> 1) * 64, wn = (wave & 1) * 64;
  const int bm = blockIdx.y * 128, bn = blockIdx.x * 128;

  f32x4 acc[4][4];
#pragma unroll
  for (int i = 0; i < 4; ++i)
#pragma unroll
    for (int j = 0; j < 4; ++j) acc[i][j] = f32x4{0.f, 0.f, 0.f, 0.f};

  const int srow = tid >> 3;                       // 0..31
  const int sg   = (tid & 7) ^ (srow & 7);         // swizzled source granule
  const bf16_t* Ap = A  + (size_t)(bm + srow) * K + sg * 8;
  const bf16_t* Bp = Bt + (size_t)(bn + srow) * K + sg * 8;
  short* Ad = As + tid * 8;
  short* Bd = Bs + tid * 8;

  for (int k0 = 0; k0 < K; k0 += 64) {
    __syncthreads();
#pragma unroll
    for (int pp = 0; pp < 4; ++pp) {
      gld16(Ap + (size_t)(pp * 32) * K + k0, Ad + pp * 2048);
      gld16(Bp + (size_t)(pp * 32) * K + k0, Bd + pp * 2048);
    }
    __syncthreads();
#pragma unroll
    for (int ks = 0; ks < 2; ++ks) {
      bf16x8 af[4], bfr[4];
#pragma unroll
      for (int i = 0; i < 4; ++i)
        af[i] = *(const bf16x8*)&As[(wm + i * 16 + l16) * 64 +
                                    (((ks * 4 + quad) ^ (l16 & 7)) << 3)];
#pragma unroll
      for (int j = 0; j < 4; ++j)
        bfr[j] = *(const bf16x8*)&Bs[(wn + j * 16 + l16) * 64 +
                                     (((ks * 4 + quad) ^ (l16 & 7)) << 3)];
#pragma unroll
      for (int i = 0; i < 4; ++i)
#pragma unroll
        for (int j = 0; j < 4; ++j)
          acc[i][j] = __builtin_amdgcn_mfma_f32_16x16x32_bf16(af[i], bfr[j], acc[i][j], 0, 0, 0);
    }
  }
#pragma unroll
  for (int i = 0; i < 4; ++i)
#pragma unroll
    for (int j = 0; j < 4; ++j) {
      const int col = bn + wn + j * 16 + l16;
      const int row0 = bm + wm + i * 16 + quad * 4;
      if (MODE == 1 && col >= 2048) {
        const int d = col - 2048;
        const int hh = d >> 6, dd = d & 63;
        const int bb = row0 >> 11, ss = row0 & 2047;
        ushort4 pk;
        pk.x = f2bf(acc[i][j][0]); pk.y = f2bf(acc[i][j][1]);
        pk.z = f2bf(acc[i][j][2]); pk.w = f2bf(acc[i][j][3]);
        *(ushort4*)(vt + ((size_t)((bb * NH + hh) * HD + dd)) * SEQ + ss) = pk;
      } else {
#pragma unroll
        for (int r = 0; r < 4; ++r) {
          if (MODE == 1)
            ((bf16_t*)Cout)[(size_t)(row0 + r) * N + col] = f2bf(acc[i][j][r]);
          else
            ((float*)Cout)[(size_t)(row0 + r) * N + col] = acc[i][j][r];
        }
      }
    }
}

// ---------------- GEMM1: qkv = xb * Wt1^T, 128x384 tile, K-granule pipeline ----
// 512 threads (8 waves 2Mx4N), per-wave C 64x96 = acc[4][6]. 32 phases (kt,ks),
// kt=0..15, ks=0..1; granule (kt,ks) = A[128x32]+B[384x32] staged 3 phases ahead
// into region (2*kt+ks)&3; region free: its previous reader (phase ph-1 for the
// stage at ph) lgkm-drained + barriered before the stage issues. vmcnt(8) keeps
// 2 granules (8 gld16) in flight; never 0 until the tail.
// LDS swizzle: slot g at row r holds source granule g ^ (r&3) ^ ((r>>2)&3)
// (2-way max on ds_read_b128); staging pre-swizzles the GLOBAL source granule.
__global__ __launch_bounds__(512, 2) void k_gqkv(const bf16_t* __restrict__ A,
                                                 const bf16_t* __restrict__ Bt,
                                                 bf16_t* __restrict__ qkv,
                                                 bf16_t* __restrict__ vt) {
  const int K = 1024;
  __shared__ __align__(16) short LA[2 * 2 * 4096];    // [buf][ks][128*32]
  __shared__ __align__(16) short LB[2 * 2 * 12288];   // [buf][ks][384*32]
  const int tid = threadIdx.x;
  const int lane = tid & 63, wave = tid >> 6;
  const int quad = lane >> 4, l16 = lane & 15;
  const int ah = wave >> 2;              // M half (64 rows)
  const int wn4 = wave & 3;              // 96-col slice

  int bid = (int)blockIdx.x;
  bid = (bid & 7) * 64 + (bid >> 3);     // XCD-contiguous (512 % 8 == 0)
  const int bm = (bid >> 3) * 128, bn = (bid & 7) * 384;

  f32x4 acc[4][6];
#pragma unroll
  for (int i = 0; i < 4; ++i)
#pragma unroll
    for (int j = 0; j < 6; ++j) acc[i][j] = f32x4{0.f, 0.f, 0.f, 0.f};

  // staging: thread t -> LDS row t>>2, granule t&3; source granule pre-swizzled
  const int sg = (tid & 3) ^ ((tid >> 2) & 3) ^ ((tid >> 4) & 3);
  const bf16_t* aS = A  + (size_t)(bm + (tid >> 2)) * K + sg * 8;
  const bf16_t* bS = Bt + (size_t)(bn + (tid >> 2)) * K + sg * 8;
  short* dA = LA + tid * 8;
  short* dB = LB + tid * 8;

  // read offsets: same granule for every frag (mi*16 / 96-base all ≡ 0 mod 16)
  const int g = quad ^ (l16 & 3) ^ ((l16 >> 2) & 3);
  const int abase = (ah * 64 + l16) * 32 + g * 8;
  const int bbase = (wn4 * 96 + l16) * 32 + g * 8;

#define WAITV(n) asm volatile("s_waitcnt vmcnt(" n ")" ::: "memory")
#define STGR(kts, kss)                                                         \
  do {                                                                         \
    const size_t kc_ = (size_t)((kts) * 64 + (kss) * 32);                      \
    const int rb_ = ((kts) & 1) * 2 + (kss);                                   \
    gld16(aS + kc_, dA + rb_ * 4096);                                          \
    gld16(bS + kc_, dB + rb_ * 12288);                                         \
    gld16(bS + (size_t)128 * 1024 + kc_, dB + rb_ * 12288 + 4096);             \
    gld16(bS + (size_t)256 * 1024 + kc_, dB + rb_ * 12288 + 8192);             \
  } while (0)
#define PHASE(kt, ks, STAGE_STMT, WAIT_STMT)                                   \
  do {                                                                         \
    const short* la_ = LA + (((kt) & 1) * 2 + (ks)) * 4096 + abase;            \
    const short* lb_ = LB + (((kt) & 1) * 2 + (ks)) * 12288 + bbase;           \
    bf16x8 af[4], bfr[6];                                                      \
    _Pragma("unroll") for (int mi = 0; mi < 4; ++mi)                           \
        af[mi] = *(const bf16x8*)(la_ + mi * 512);                             \
    _Pragma("unroll") for (int nj = 0; nj < 6; ++nj)                           \
        bfr[nj] = *(const bf16x8*)(lb_ + nj * 512);                            \
    STAGE_STMT;                                                                \
    WAIT_STMT;                                                                 \
    __builtin_amdgcn_s_barrier();                                              \
    __builtin_amdgcn_s_setprio(1);                                             \
    _Pragma("unroll") for (int mi = 0; mi < 4; ++mi)                           \
      _Pragma("unroll") for (int nj = 0; nj < 6; ++nj)                         \
        acc[mi][nj] = __builtin_amdgcn_mfma_f32_16x16x32_bf16(                 \
            af[mi], bfr[nj], acc[mi][nj], 0, 0, 0);                            \
    __builtin_amdgcn_s_setprio(0);                                             \
    asm volatile("s_waitcnt lgkmcnt(0)" ::: "memory");                         \
    __builtin_amdgcn_s_barrier();                                              \
  } while (0)

  // prologue: granules for phases 0,1,2 (12 loads); drain g0 (-> 8 in flight)
  STGR(0, 0); STGR(0, 1); STGR(1, 0);
  WAITV("8");
  __builtin_amdgcn_s_barrier();

  // phases 0..28: uniform; stage granule ph+3 (g3..g31); 2 granules in flight
#pragma unroll 1
  for (int ph = 0; ph < 29; ++ph) {
    const int kt = ph >> 1, ks = ph & 1;
    const int pk = ph + 3;
    PHASE(kt, ks, STGR(pk >> 1, pk & 1), WAITV("8"));
  }
  // tail: phases 29,30,31; no stages; drain 8 -> 4 -> 0
  PHASE(14, 1, (void)0, WAITV("4"));
  PHASE(15, 0, (void)0, WAITV("0"));
  PHASE(15, 1, (void)0, (void)0);

  // epilogue: C row = quad*4+reg, col = l16; cols>=2048 -> V^T packed
#pragma unroll
  for (int mi = 0; mi < 4; ++mi)
#pragma unroll
    for (int nj = 0; nj < 6; ++nj) {
      const int col = bn + wn4 * 96 + nj * 16 + l16;
      const int row0 = bm + ah * 64 + mi * 16 + quad * 4;
      if (col >= 2048) {
        const int d = col - 2048;
        const int hh = d >> 6, dd = d & 63;
        const int bb = row0 >> 11, ss = row0 & 2047;
        ushort4 pk;
        pk.x = f2bf(acc[mi][nj][0]); pk.y = f2bf(acc[mi][nj][1]);
        pk.z = f2bf(acc[mi][nj][2]); pk.w = f2bf(acc[mi][nj][3]);
        *(ushort4*)(vt + ((size_t)((bb * NH + hh) * HD + dd)) * SEQ + ss) = pk;
      } else {
#pragma unroll
        for (int r = 0; r < 4; ++r)
          qkv[(size_t)(row0 + r) * QKV_W + col] = f2bf(acc[mi][nj][r]);
      }
    }
#undef WAITV
#undef STGR
#undef PHASE
}

// ---------------- flash attention ----------------
// 512 blocks, XCD-swizzled. Block: 128 Q-rows (4 waves x 32q), Q-tiles (p,15-p)
// => uniform 34 KV-iters. KV dbuf + cross-iter prefetch, 1 barrier/iter.
// Q pre-scaled by 0.125*log2e => p = exp2(s'), shift-free (cancels in norm).
// Swapped QK^T: S^T = mfma(K, Q) so each lane holds P[q=l16][k=jn*16+quad*4+r];
// PV A-frags built in-register via cvt_pk + permlane32/16 swaps — no P LDS.
#define QSCALE 0.18033688011112042f   // 0.125 * log2(e)
__global__ __launch_bounds__(256, 2) void k_attn(const bf16_t* __restrict__ qkv,
                                                 const bf16_t* __restrict__ vt,
                                                 bf16_t* __restrict__ y) {
  __shared__ __align__(16) short KV[2][4][64 * 32];  // [buf][K0,K1,V0,V1]
  const int tid = threadIdx.x;
  const int lane = tid & 63;
  const int quad = lane >> 4, l16 = lane & 15;
  const int wave = tid >> 6;
  const int l = blockIdx.x;
  const int p = (l >> 3) & 7;                    // pair index 0..7
  const int g = ((l >> 6) << 3) | (l & 7);       // (h,b) group, const per XCD slice
  const int h = g & 15, b = g >> 4;
  const size_t bbase = (size_t)b * SEQ * QKV_W;
  const int srow = tid >> 2;            // staging row 0..63
  const int sc8  = (tid & 3) * 8;       // staging col 0,8,16,24
  const bf16_t* kbase = qkv + bbase + (size_t)srow * QKV_W + DM + h * HD + sc8;
  const bf16_t* vbase = vt + ((size_t)(b * NH + h) * HD + srow) * SEQ + sc8;

#define ISSUE(kv0, buf)                                              \
  do {                                                               \
    gld16(kbase + (size_t)(kv0) * QKV_W,      &KV[buf][0][tid * 8]); \
    gld16(kbase + (size_t)(kv0) * QKV_W + 32, &KV[buf][1][tid * 8]); \
    gld16(vbase + (kv0),                      &KV[buf][2][tid * 8]); \
    gld16(vbase + (kv0) + 32,                 &KV[buf][3][tid * 8]); \
  } while (0)

  int bufp = 0;
  ISSUE(0, 0);
  for (int half = 0; half < 2; ++half) {
    const int qt = half ? (15 - p) : p;
    const int qb = qt * 128 + wave * 32;         // wave's first q row
    // load + pre-scale Q fragments: aq[mi][kk]  (B-operand; layout == A layout)
    bf16x8 aq[2][2];
#pragma unroll
    for (int mi = 0; mi < 2; ++mi)
#pragma unroll
      for (int kk = 0; kk < 2; ++kk) {
        const bf16_t* qp = qkv + bbase + (size_t)(qb + mi * 16 + l16) * QKV_W +
                           h * HD + kk * 32 + quad * 8;
        bf16x8 raw = *(const bf16x8*)qp;
        bf16x8 sc;
#pragma unroll
        for (int e = 0; e < 8; ++e)
          sc[e] = (short)f2bf(bf2f((unsigned short)raw[e]) * QSCALE);
        aq[mi][kk] = sc;
      }
    f32x4 o[2][4];
    float lsum[2];
#pragma unroll
    for (int mi = 0; mi < 2; ++mi) {
      lsum[mi] = 0.f;
#pragma unroll
      for (int jn = 0; jn < 4; ++jn) o[mi][jn] = f32x4{0.f, 0.f, 0.f, 0.f};
    }
    const int qr0 = qb + l16;                    // this lane's q row (mi=0)

    const int jmax = 2 * qt + 1;
    for (int j = 0; j <= jmax; ++j) {
      const int kv0 = j * 64;
      __syncthreads();   // drains this buf's loads; WAR-protects prefetch target
      if (j < jmax)          ISSUE(kv0 + 64, bufp ^ 1);
      else if (half == 0)    ISSUE(0, bufp ^ 1);
      if (kv0 <= qb + 31) {  // else: fully masked for this wave — skip
        const bool needmask = (kv0 + 63 > qb);
        const short* Kc0 = &KV[bufp][0][0];
        const short* Kc1 = &KV[bufp][1][0];
        const short* Vc0 = &KV[bufp][2][0];
        const short* Vc1 = &KV[bufp][3][0];

        // S^T frags: st[jn][mi]; row = kv (jn*16+quad*4+r), col = q (mi*16+l16)
        f32x4 st[4][2];
#pragma unroll
        for (int jn = 0; jn < 4; ++jn) {
          bf16x8 ak0 = *(const bf16x8*)&Kc0[(jn * 16 + l16) * 32 + quad * 8];
          bf16x8 ak1 = *(const bf16x8*)&Kc1[(jn * 16 + l16) * 32 + quad * 8];
#pragma unroll
          for (int mi = 0; mi < 2; ++mi) {
            f32x4 s4 = f32x4{0.f, 0.f, 0.f, 0.f};
            s4 = __builtin_amdgcn_mfma_f32_16x16x32_bf16(ak0, aq[mi][0], s4, 0, 0, 0);
            s4 = __builtin_amdgcn_mfma_f32_16x16x32_bf16(ak1, aq[mi][1], s4, 0, 0, 0);
            st[jn][mi] = s4;
          }
        }
        // p = exp2(s'); mask near diagonal; pack r-pairs to bf16x2
        unsigned pk[4][2][2];
#pragma unroll
        for (int jn = 0; jn < 4; ++jn)
#pragma unroll
          for (int mi = 0; mi < 2; ++mi) {
            const int kvb = kv0 + jn * 16 + quad * 4;
            const int qr = qr0 + mi * 16;
            float e[4];
#pragma unroll
            for (int r = 0; r < 4; ++r) {
              float v = __builtin_amdgcn_exp2f(st[jn][mi][r]);
              if (needmask) v = (kvb + r <= qr) ? v : 0.f;
              lsum[mi] += v;
              e[r] = v;
            }
            pk[jn][mi][0] = cvt_pk_bf16(e[0], e[1]);
            pk[jn][mi][1] = cvt_pk_bf16(e[2], e[3]);
          }
        // redistribute across quads -> PV A-frags ap[mi][ks]
        bf16x8 ap[2][2];
#pragma unroll
        for (int mi = 0; mi < 2; ++mi)
#pragma unroll
          for (int ks = 0; ks < 2; ++ks) {
            unsigned a0 = pk[2 * ks][mi][0], b0 = pk[2 * ks + 1][mi][0];
            permlane32_swap(a0, b0);
            permlane16_swap(a0, b0);
            unsigned a1 = pk[2 * ks][mi][1], b1 = pk[2 * ks + 1][mi][1];
            permlane32_swap(a1, b1);
            permlane16_swap(a1, b1);
            union { u32x4 u; bf16x8 s; } f;
            f.u = (u32x4){a0, a1, b0, b1};
            ap[mi][ks] = f.s;
          }
        // O += P V  (V frags shared across mi)
#pragma unroll
        for (int ks = 0; ks < 2; ++ks) {
          const short* Vc = ks ? Vc1 : Vc0;
#pragma unroll
          for (int jn = 0; jn < 4; ++jn) {
            bf16x8 bv = *(const bf16x8*)&Vc[(jn * 16 + l16) * 32 + quad * 8];
            o[0][jn] = __builtin_amdgcn_mfma_f32_16x16x32_bf16(ap[0][ks], bv, o[0][jn], 0, 0, 0);
            o[1][jn] = __builtin_amdgcn_mfma_f32_16x16x32_bf16(ap[1][ks], bv, o[1][jn], 0, 0, 0);
          }
        }
      }
      bufp ^= 1;
    }
    // normalize + write: lane holds full row-sum for q = l16 (+mi*16) after
    // quad-reduce; redistribute inv to output rows (quad*4+r) via shfl.
#pragma unroll
    for (int mi = 0; mi < 2; ++mi) {
      float s = lsum[mi];
      s += __shfl_xor(s, 16, 64);
      s += __shfl_xor(s, 32, 64);
      const float inv = 1.0f / s;
#pragma unroll
      for (int r = 0; r < 4; ++r) {
        const float invr = __shfl(inv, quad * 4 + r, 64);
        const int qr = qb + mi * 16 + quad * 4 + r;
        bf16_t* yp = y + ((size_t)b * SEQ + qr) * DM + h * HD;
#pragma unroll
        for (int jn = 0; jn < 4; ++jn)
          yp[jn * 16 + l16] = f2bf(o[mi][jn][r] * invr);
      }
    }
  }
#undef ISSUE
}

extern "C" void kernel_launch(void* const* d_in, const int* in_sizes, int n_in,
                              void* d_out, int out_size, void* d_ws, size_t ws_size,
                              hipStream_t stream) {
  const float* x     = (const float*)d_in[0];
  const float* Wqkv  = (const float*)d_in[1];
  const float* Wproj = (const float*)d_in[2];
  float* out = (float*)d_out;
  char* ws = (char*)d_ws;
  // ws layout (72 MiB):
  bf16_t* qkv = (bf16_t*)(ws);                 // 48 MiB (V third unused)
  bf16_t* Wt1 = (bf16_t*)(ws + 50331648);      // 6 MiB
  bf16_t* Wt2 = (bf16_t*)(ws + 56623104);      // 2 MiB
  bf16_t* xb  = (bf16_t*)(ws + 58720256);      // 16 MiB (dead after GEMM1)
  bf16_t* y   = xb;                            // attn output aliases xb
  // V^T parked in d_out's first 16 MiB; dead before GEMM2 overwrites d_out.
  bf16_t* vt  = (bf16_t*)d_out;

  k_transpose<<<dim3(QKV_W / 32, DM / 32), dim3(32, 8), 0, stream>>>(Wqkv, Wt1, DM, QKV_W);
  k_transpose<<<dim3(DM / 32, DM / 32), dim3(32, 8), 0, stream>>>(Wproj, Wt2, DM, DM);
  k_cvt<<<(BATCH * SEQ * DM) / (4 * 256), 256, 0, stream>>>(x, xb);
  k_gqkv<<<512, 512, 0, stream>>>(xb, Wt1, qkv, vt);
  k_rope<<<(BATCH * SEQ * NH * 32) / 256, 256, 0, stream>>>(qkv);
  k_attn<<<512, 256, 0, stream>>>(qkv, vt, y);
  k_gemm<0><<<dim3(DM / 128, (BATCH * SEQ) / 128), 256, 0, stream>>>(
      y, Wt2, out, nullptr, BATCH * SEQ, DM, DM);
}

// Round 5
// 252.273 us; speedup vs baseline: 1.0261x; 1.0261x over previous
//
#include <hip/hip_runtime.h>

// Causal self-attention fwd: x(4,2048,1024)fp32, W_qkv(1024,3072), W_proj(1024,1024)
// Pipeline: [transpose W->bf16] [x->bf16] [GEMM1 qkv + fused V-transpose] [RoPE q,k]
//           [flash attn] [GEMM2 out]
// R5: attn 32q/wave, paired Q-tiles, exp2 shift-free softmax.
// R6: swapped QK^T + in-register P via cvt_pk_bf16 + permlane swaps (no P LDS).
// R9: K-granule pipeline w/ 64B LDS rows -> 5.24M bank conflicts (4-way: a 64B
//     row can't XOR-spread b128 reads over 32 banks), 71.5us. Lesson: the
//     0-conflict pattern REQUIRES 128B rows + 8-slot XOR.
// R10: counted-vmcnt pipeline on PROVEN 128B-row geometry. BM=128 BN=384 BK=64,
//     grid 512 = 2 exact rounds @1 block/CU. Stage unit = 64-row sweep (1 gld16
//     per thread); 8 units/K-tile (2A+6B). Per K-tile: PH0{stage kt+1 u0-3;
//     vmcnt(4) (never 0); barrier+fence; 10 ds_read ks0; 24 MFMA setprio} PH1
//     {stage kt+1 u4-7; 10 ds_read ks1; 24 MFMA; barrier}. WAR: each stage is
//     >=1 barrier after its region's readers drained (reads drain via MFMA reg
//     dep before trailing barrier). Tail kt=15: vmcnt(0) once.

#define BATCH 4
#define SEQ   2048
#define DM    1024
#define NH    16
#define HD    64
#define QKV_W 3072

typedef short bf16x8 __attribute__((ext_vector_type(8)));
typedef float f32x4  __attribute__((ext_vector_type(4)));
typedef unsigned u32x4 __attribute__((ext_vector_type(4)));
typedef unsigned short bf16_t;

__device__ __forceinline__ unsigned short f2bf(float f) {
  unsigned u = __float_as_uint(f);
  u += 0x7fffu + ((u >> 16) & 1u);   // round-to-nearest-even
  return (unsigned short)(u >> 16);
}
__device__ __forceinline__ float bf2f(unsigned short s) {
  return __uint_as_float((unsigned)s << 16);
}
// async global->LDS, 16B per lane; LDS dest is wave-uniform base + lane*16
__device__ __forceinline__ void gld16(const void* g, void* l) {
  __builtin_amdgcn_global_load_lds(
      (const __attribute__((address_space(1))) unsigned int*)g,
      (__attribute__((address_space(3))) unsigned int*)l, 16, 0, 0);
}
// packed f32x2 -> bf16x2 (RTNE), lo=a hi=b
__device__ __forceinline__ unsigned cvt_pk_bf16(float a, float b) {
  unsigned r;
  asm("v_cvt_pk_bf16_f32 %0, %1, %2" : "=v"(r) : "v"(a), "v"(b));
  return r;
}
// a.rows{2,3} <-> b.rows{0,1}  (rows = 16-lane groups)
__device__ __forceinline__ void permlane32_swap(unsigned& a, unsigned& b) {
  asm("v_permlane32_swap_b32 %0, %1" : "+v"(a), "+v"(b));
}
// a.rows{1,3} <-> b.rows{0,2}
__device__ __forceinline__ void permlane16_swap(unsigned& a, unsigned& b) {
  asm("v_permlane16_swap_b32 %0, %1" : "+v"(a), "+v"(b));
}

// ---------------- W[K][N] fp32 -> Wt[N][K] bf16 ----------------
__global__ __launch_bounds__(256) void k_transpose(const float* __restrict__ W,
                                                   bf16_t* __restrict__ Wt,
                                                   int K, int N) {
  __shared__ float tile[32][33];
  const int tx = threadIdx.x, ty = threadIdx.y;   // (32,8)
  const int n0 = blockIdx.x * 32, k0 = blockIdx.y * 32;
#pragma unroll
  for (int j = 0; j < 4; ++j)
    tile[ty + j * 8][tx] = W[(size_t)(k0 + ty + j * 8) * N + n0 + tx];
  __syncthreads();
#pragma unroll
  for (int j = 0; j < 4; ++j)
    Wt[(size_t)(n0 + ty + j * 8) * K + k0 + tx] = f2bf(tile[tx][ty + j * 8]);
}

// ---------------- fp32 -> bf16 elementwise ----------------
__global__ __launch_bounds__(256) void k_cvt(const float* __restrict__ x,
                                             bf16_t* __restrict__ xb) {
  const int i = (blockIdx.x * 256 + threadIdx.x) * 4;
  float4 v = *(const float4*)(x + i);
  unsigned lo = (unsigned)f2bf(v.x) | ((unsigned)f2bf(v.y) << 16);
  unsigned hi = (unsigned)f2bf(v.z) | ((unsigned)f2bf(v.w) << 16);
  *(uint2*)(xb + i) = make_uint2(lo, hi);
}

// ---------------- RoPE in place on q,k sections of qkv ----------------
__global__ __launch_bounds__(256) void k_rope(bf16_t* __restrict__ qkv) {
  const int t = blockIdx.x * 256 + threadIdx.x;
  const int i = t & 31;            // freq index 0..31
  const int h = (t >> 5) & 15;     // head
  const int s = (t >> 9) & 2047;   // position
  const int b = t >> 20;
  const float inv = __expf((float)i * -0.28782313662425575f); // -ln(10000)/32
  float sn, cs;
  sincosf((float)s * inv, &sn, &cs);
  size_t base = ((size_t)(b * SEQ + s)) * QKV_W + h * HD + 2 * i;
#pragma unroll
  for (int part = 0; part < 2; ++part) {      // q then k
    unsigned u = *(unsigned*)(qkv + base + part * DM);
    float e = bf2f((unsigned short)(u & 0xffffu));
    float o = bf2f((unsigned short)(u >> 16));
    unsigned short e2 = f2bf(e * cs - o * sn);
    unsigned short o2 = f2bf(e * sn + o * cs);
    *(unsigned*)(qkv + base + part * DM) = (unsigned)e2 | ((unsigned)o2 << 16);
  }
}

// ---------------- 128x128 bf16 GEMM (2-phase) — used for GEMM2 ----------------
template<int MODE>
__global__ __launch_bounds__(256) void k_gemm(const bf16_t* __restrict__ A,
                                              const bf16_t* __restrict__ Bt,
                                              void* __restrict__ Cout,
                                              bf16_t* __restrict__ vt,
                                              int M, int N, int K) {
  __shared__ __align__(16) short As[128 * 64];
  __shared__ __align__(16) short Bs[128 * 64];
  const int tid = threadIdx.x;
  const int wave = tid >> 6, lane = tid & 63;
  const int quad = lane >> 4, l16 = lane & 15;
  const int wm = (wave >> 1) * 64, wn = (wave & 1) * 64;
  const int bm = blockIdx.y * 128, bn = blockIdx.x * 128;

  f32x4 acc[4][4];
#pragma unroll
  for (int i = 0; i < 4; ++i)
#pragma unroll
    for (int j = 0; j < 4; ++j) acc[i][j] = f32x4{0.f, 0.f, 0.f, 0.f};

  const int srow = tid >> 3;                       // 0..31
  const int sg   = (tid & 7) ^ (srow & 7);         // swizzled source granule
  const bf16_t* Ap = A  + (size_t)(bm + srow) * K + sg * 8;
  const bf16_t* Bp = Bt + (size_t)(bn + srow) * K + sg * 8;
  short* Ad = As + tid * 8;
  short* Bd = Bs + tid * 8;

  for (int k0 = 0; k0 < K; k0 += 64) {
    __syncthreads();
#pragma unroll
    for (int pp = 0; pp < 4; ++pp) {
      gld16(Ap + (size_t)(pp * 32) * K + k0, Ad + pp * 2048);
      gld16(Bp + (size_t)(pp * 32) * K + k0, Bd + pp * 2048);
    }
    __syncthreads();
#pragma unroll
    for (int ks = 0; ks < 2; ++ks) {
      bf16x8 af[4], bfr[4];
#pragma unroll
      for (int i = 0; i < 4; ++i)
        af[i] = *(const bf16x8*)&As[(wm + i * 16 + l16) * 64 +
                                    (((ks * 4 + quad) ^ (l16 & 7)) << 3)];
#pragma unroll
      for (int j = 0; j < 4; ++j)
        bfr[j] = *(const bf16x8*)&Bs[(wn + j * 16 + l16) * 64 +
                                     (((ks * 4 + quad) ^ (l16 & 7)) << 3)];
#pragma unroll
      for (int i = 0; i < 4; ++i)
#pragma unroll
        for (int j = 0; j < 4; ++j)
          acc[i][j] = __builtin_amdgcn_mfma_f32_16x16x32_bf16(af[i], bfr[j], acc[i][j], 0, 0, 0);
    }
  }
#pragma unroll
  for (int i = 0; i < 4; ++i)
#pragma unroll
    for (int j = 0; j < 4; ++j) {
      const int col = bn + wn + j * 16 + l16;
      const int row0 = bm + wm + i * 16 + quad * 4;
      if (MODE == 1 && col >= 2048) {
        const int d = col - 2048;
        const int hh = d >> 6, dd = d & 63;
        const int bb = row0 >> 11, ss = row0 & 2047;
        ushort4 pk;
        pk.x = f2bf(acc[i][j][0]); pk.y = f2bf(acc[i][j][1]);
        pk.z = f2bf(acc[i][j][2]); pk.w = f2bf(acc[i][j][3]);
        *(ushort4*)(vt + ((size_t)((bb * NH + hh) * HD + dd)) * SEQ + ss) = pk;
      } else {
#pragma unroll
        for (int r = 0; r < 4; ++r) {
          if (MODE == 1)
            ((bf16_t*)Cout)[(size_t)(row0 + r) * N + col] = f2bf(acc[i][j][r]);
          else
            ((float*)Cout)[(size_t)(row0 + r) * N + col] = acc[i][j][r];
        }
      }
    }
}

// ---------------- GEMM1: qkv = xb * Wt1^T, 128x384, counted-vmcnt pipeline ----
// 512 threads (8 waves 2Mx4N), per-wave C 64x96 = acc[4][6]. LDS: proven
// [row][64-short] 128B rows, slot XOR (ks*4+quad)^(l16&7) (0-conflict pattern).
// Stage unit = 64-row sweep (1 gld16/thread); K-tile = units A0,A1,B0..B5.
__global__ __launch_bounds__(512, 2) void k_gqkv(const bf16_t* __restrict__ A,
                                                 const bf16_t* __restrict__ Bt,
                                                 bf16_t* __restrict__ qkv,
                                                 bf16_t* __restrict__ vt) {
  const int K = 1024;
  __shared__ __align__(16) short LA[2][128 * 64];   // 32KB
  __shared__ __align__(16) short LB[2][384 * 64];   // 96KB
  const int tid = threadIdx.x;
  const int lane = tid & 63, wave = tid >> 6;
  const int quad = lane >> 4, l16 = lane & 15;
  const int ah = wave >> 2;              // M half: rows ah*64..+63
  const int wn4 = wave & 3;              // 96-col slice

  const int b0 = (int)blockIdx.x;
  const int wg = (b0 & 7) * 64 + (b0 >> 3);   // XCD-contiguous (512 % 8 == 0)
  const int bm = (wg >> 3) * 128, bn = (wg & 7) * 384;

  f32x4 acc[4][6];
#pragma unroll
  for (int i = 0; i < 4; ++i)
#pragma unroll
    for (int j = 0; j < 6; ++j) acc[i][j] = f32x4{0.f, 0.f, 0.f, 0.f};

  // staging: thread t -> row t>>3 (0..63) of the unit, slot t&7;
  // source granule pre-swizzled so slot s at row r holds granule s^(r&7)
  const int srow = tid >> 3;
  const int sg   = (tid & 7) ^ (srow & 7);
  const bf16_t* aS = A  + (size_t)(bm + srow) * K + sg * 8;
  const bf16_t* bS = Bt + (size_t)(bn + srow) * K + sg * 8;

  const int arow = ah * 64 + l16;
  const int brow = wn4 * 96 + l16;
  const int xs = l16 & 7;

#define STGA(buf, n, kt) \
  gld16(aS + (size_t)((n) * 64) * K + (kt) * 64, &LA[buf][(n) * 4096 + tid * 8])
#define STGB(buf, n, kt) \
  gld16(bS + (size_t)((n) * 64) * K + (kt) * 64, &LB[buf][(n) * 4096 + tid * 8])
#define STG03(buf, kt) \
  do { STGA(buf, 0, kt); STGA(buf, 1, kt); STGB(buf, 0, kt); STGB(buf, 1, kt); } while (0)
#define STG47(buf, kt) \
  do { STGB(buf, 2, kt); STGB(buf, 3, kt); STGB(buf, 4, kt); STGB(buf, 5, kt); } while (0)
#define READS(buf, ks, af, bfr)                                                \
  do {                                                                         \
    const int slot_ = ((((ks) * 4 + quad) ^ xs) << 3);                         \
    _Pragma("unroll") for (int mi = 0; mi < 4; ++mi)                           \
        af[mi] = *(const bf16x8*)&LA[buf][(arow + mi * 16) * 64 + slot_];      \
    _Pragma("unroll") for (int nj = 0; nj < 6; ++nj)                           \
        bfr[nj] = *(const bf16x8*)&LB[buf][(brow + nj * 16) * 64 + slot_];     \
  } while (0)
#define MFMAS(af, bfr)                                                         \
  do {                                                                         \
    __builtin_amdgcn_s_setprio(1);                                             \
    _Pragma("unroll") for (int mi = 0; mi < 4; ++mi)                           \
      _Pragma("unroll") for (int nj = 0; nj < 6; ++nj)                         \
        acc[mi][nj] = __builtin_amdgcn_mfma_f32_16x16x32_bf16(                 \
            af[mi], bfr[nj], acc[mi][nj], 0, 0, 0);                            \
    __builtin_amdgcn_s_setprio(0);                                             \
  } while (0)

  // prologue: stage all 8 units of K-tile 0 into buf 0
  STG03(0, 0); STG47(0, 0);            // 8 in flight

#pragma unroll 1
  for (int kt = 0; kt < 15; ++kt) {
    const int cb = kt & 1, nb = cb ^ 1;
    // PH0: stage next tile's first half, retire current tile's 8 loads
    STG03(nb, kt + 1);                                   // in flight: 8 + 4
    asm volatile("s_waitcnt vmcnt(4)" ::: "memory");     // kt fully retired
    __builtin_amdgcn_s_barrier();                        // all waves' vmcnt done
    asm volatile("" ::: "memory");                       // no load hoist above bar
    {
      bf16x8 af[4], bfr[6];
      READS(cb, 0, af, bfr);
      MFMAS(af, bfr);
    }
    // PH1: stage next tile's second half (WAR: region's readers drained >=1
    // barrier ago), read ks1 (resident since PH0 barrier), compute, barrier.
    STG47(nb, kt + 1);                                   // in flight: 4 + 4
    {
      bf16x8 af[4], bfr[6];
      READS(cb, 1, af, bfr);
      MFMAS(af, bfr);
    }
    __builtin_amdgcn_s_barrier();                        // WAR for next PH0 stage
  }
  // tail: kt = 15 (buf 1), nothing left to stage
  asm volatile("s_waitcnt vmcnt(0)" ::: "memory");
  __builtin_amdgcn_s_barrier();
  asm volatile("" ::: "memory");
  {
    bf16x8 af[4], bfr[6];
    READS(1, 0, af, bfr);
    MFMAS(af, bfr);
  }
  {
    bf16x8 af[4], bfr[6];
    READS(1, 1, af, bfr);
    MFMAS(af, bfr);
  }

  // epilogue: C row = quad*4+reg, col = l16; cols>=2048 -> V^T packed
#pragma unroll
  for (int mi = 0; mi < 4; ++mi)
#pragma unroll
    for (int nj = 0; nj < 6; ++nj) {
      const int col = bn + wn4 * 96 + nj * 16 + l16;
      const int row0 = bm + ah * 64 + mi * 16 + quad * 4;
      if (col >= 2048) {
        const int d = col - 2048;
        const int hh = d >> 6, dd = d & 63;
        const int bb = row0 >> 11, ss = row0 & 2047;
        ushort4 pk;
        pk.x = f2bf(acc[mi][nj][0]); pk.y = f2bf(acc[mi][nj][1]);
        pk.z = f2bf(acc[mi][nj][2]); pk.w = f2bf(acc[mi][nj][3]);
        *(ushort4*)(vt + ((size_t)((bb * NH + hh) * HD + dd)) * SEQ + ss) = pk;
      } else {
#pragma unroll
        for (int r = 0; r < 4; ++r)
          qkv[(size_t)(row0 + r) * QKV_W + col] = f2bf(acc[mi][nj][r]);
      }
    }
#undef STGA
#undef STGB
#undef STG03
#undef STG47
#undef READS
#undef MFMAS
}

// ---------------- flash attention ----------------
// 512 blocks, XCD-swizzled. Block: 128 Q-rows (4 waves x 32q), Q-tiles (p,15-p)
// => uniform 34 KV-iters. KV dbuf + cross-iter prefetch, 1 barrier/iter.
// Q pre-scaled by 0.125*log2e => p = exp2(s'), shift-free (cancels in norm).
// Swapped QK^T: S^T = mfma(K, Q) so each lane holds P[q=l16][k=jn*16+quad*4+r];
// PV A-frags built in-register via cvt_pk + permlane32/16 swaps — no P LDS.
#define QSCALE 0.18033688011112042f   // 0.125 * log2(e)
__global__ __launch_bounds__(256, 2) void k_attn(const bf16_t* __restrict__ qkv,
                                                 const bf16_t* __restrict__ vt,
                                                 bf16_t* __restrict__ y) {
  __shared__ __align__(16) short KV[2][4][64 * 32];  // [buf][K0,K1,V0,V1]
  const int tid = threadIdx.x;
  const int lane = tid & 63;
  const int quad = lane >> 4, l16 = lane & 15;
  const int wave = tid >> 6;
  const int l = blockIdx.x;
  const int p = (l >> 3) & 7;                    // pair index 0..7
  const int g = ((l >> 6) << 3) | (l & 7);       // (h,b) group, const per XCD slice
  const int h = g & 15, b = g >> 4;
  const size_t bbase = (size_t)b * SEQ * QKV_W;
  const int srow = tid >> 2;            // staging row 0..63
  const int sc8  = (tid & 3) * 8;       // staging col 0,8,16,24
  const bf16_t* kbase = qkv + bbase + (size_t)srow * QKV_W + DM + h * HD + sc8;
  const bf16_t* vbase = vt + ((size_t)(b * NH + h) * HD + srow) * SEQ + sc8;

#define ISSUE(kv0, buf)                                              \
  do {                                                               \
    gld16(kbase + (size_t)(kv0) * QKV_W,      &KV[buf][0][tid * 8]); \
    gld16(kbase + (size_t)(kv0) * QKV_W + 32, &KV[buf][1][tid * 8]); \
    gld16(vbase + (kv0),                      &KV[buf][2][tid * 8]); \
    gld16(vbase + (kv0) + 32,                 &KV[buf][3][tid * 8]); \
  } while (0)

  int bufp = 0;
  ISSUE(0, 0);
  for (int half = 0; half < 2; ++half) {
    const int qt = half ? (15 - p) : p;
    const int qb = qt * 128 + wave * 32;         // wave's first q row
    // load + pre-scale Q fragments: aq[mi][kk]  (B-operand; layout == A layout)
    bf16x8 aq[2][2];
#pragma unroll
    for (int mi = 0; mi < 2; ++mi)
#pragma unroll
      for (int kk = 0; kk < 2; ++kk) {
        const bf16_t* qp = qkv + bbase + (size_t)(qb + mi * 16 + l16) * QKV_W +
                           h * HD + kk * 32 + quad * 8;
        bf16x8 raw = *(const bf16x8*)qp;
        bf16x8 sc;
#pragma unroll
        for (int e = 0; e < 8; ++e)
          sc[e] = (short)f2bf(bf2f((unsigned short)raw[e]) * QSCALE);
        aq[mi][kk] = sc;
      }
    f32x4 o[2][4];
    float lsum[2];
#pragma unroll
    for (int mi = 0; mi < 2; ++mi) {
      lsum[mi] = 0.f;
#pragma unroll
      for (int jn = 0; jn < 4; ++jn) o[mi][jn] = f32x4{0.f, 0.f, 0.f, 0.f};
    }
    const int qr0 = qb + l16;                    // this lane's q row (mi=0)

    const int jmax = 2 * qt + 1;
    for (int j = 0; j <= jmax; ++j) {
      const int kv0 = j * 64;
      __syncthreads();   // drains this buf's loads; WAR-protects prefetch target
      if (j < jmax)          ISSUE(kv0 + 64, bufp ^ 1);
      else if (half == 0)    ISSUE(0, bufp ^ 1);
      if (kv0 <= qb + 31) {  // else: fully masked for this wave — skip
        const bool needmask = (kv0 + 63 > qb);
        const short* Kc0 = &KV[bufp][0][0];
        const short* Kc1 = &KV[bufp][1][0];
        const short* Vc0 = &KV[bufp][2][0];
        const short* Vc1 = &KV[bufp][3][0];

        // S^T frags: st[jn][mi]; row = kv (jn*16+quad*4+r), col = q (mi*16+l16)
        f32x4 st[4][2];
#pragma unroll
        for (int jn = 0; jn < 4; ++jn) {
          bf16x8 ak0 = *(const bf16x8*)&Kc0[(jn * 16 + l16) * 32 + quad * 8];
          bf16x8 ak1 = *(const bf16x8*)&Kc1[(jn * 16 + l16) * 32 + quad * 8];
#pragma unroll
          for (int mi = 0; mi < 2; ++mi) {
            f32x4 s4 = f32x4{0.f, 0.f, 0.f, 0.f};
            s4 = __builtin_amdgcn_mfma_f32_16x16x32_bf16(ak0, aq[mi][0], s4, 0, 0, 0);
            s4 = __builtin_amdgcn_mfma_f32_16x16x32_bf16(ak1, aq[mi][1], s4, 0, 0, 0);
            st[jn][mi] = s4;
          }
        }
        // p = exp2(s'); mask near diagonal; pack r-pairs to bf16x2
        unsigned pk[4][2][2];
#pragma unroll
        for (int jn = 0; jn < 4; ++jn)
#pragma unroll
          for (int mi = 0; mi < 2; ++mi) {
            const int kvb = kv0 + jn * 16 + quad * 4;
            const int qr = qr0 + mi * 16;
            float e[4];
#pragma unroll
            for (int r = 0; r < 4; ++r) {
              float v = __builtin_amdgcn_exp2f(st[jn][mi][r]);
              if (needmask) v = (kvb + r <= qr) ? v : 0.f;
              lsum[mi] += v;
              e[r] = v;
            }
            pk[jn][mi][0] = cvt_pk_bf16(e[0], e[1]);
            pk[jn][mi][1] = cvt_pk_bf16(e[2], e[3]);
          }
        // redistribute across quads -> PV A-frags ap[mi][ks]
        bf16x8 ap[2][2];
#pragma unroll
        for (int mi = 0; mi < 2; ++mi)
#pragma unroll
          for (int ks = 0; ks < 2; ++ks) {
            unsigned a0 = pk[2 * ks][mi][0], b0 = pk[2 * ks + 1][mi][0];
            permlane32_swap(a0, b0);
            permlane16_swap(a0, b0);
            unsigned a1 = pk[2 * ks][mi][1], b1 = pk[2 * ks + 1][mi][1];
            permlane32_swap(a1, b1);
            permlane16_swap(a1, b1);
            union { u32x4 u; bf16x8 s; } f;
            f.u = (u32x4){a0, a1, b0, b1};
            ap[mi][ks] = f.s;
          }
        // O += P V  (V frags shared across mi)
#pragma unroll
        for (int ks = 0; ks < 2; ++ks) {
          const short* Vc = ks ? Vc1 : Vc0;
#pragma unroll
          for (int jn = 0; jn < 4; ++jn) {
            bf16x8 bv = *(const bf16x8*)&Vc[(jn * 16 + l16) * 32 + quad * 8];
            o[0][jn] = __builtin_amdgcn_mfma_f32_16x16x32_bf16(ap[0][ks], bv, o[0][jn], 0, 0, 0);
            o[1][jn] = __builtin_amdgcn_mfma_f32_16x16x32_bf16(ap[1][ks], bv, o[1][jn], 0, 0, 0);
          }
        }
      }
      bufp ^= 1;
    }
    // normalize + write: lane holds full row-sum for q = l16 (+mi*16) after
    // quad-reduce; redistribute inv to output rows (quad*4+r) via shfl.
#pragma unroll
    for (int mi = 0; mi < 2; ++mi) {
      float s = lsum[mi];
      s += __shfl_xor(s, 16, 64);
      s += __shfl_xor(s, 32, 64);
      const float inv = 1.0f / s;
#pragma unroll
      for (int r = 0; r < 4; ++r) {
        const float invr = __shfl(inv, quad * 4 + r, 64);
        const int qr = qb + mi * 16 + quad * 4 + r;
        bf16_t* yp = y + ((size_t)b * SEQ + qr) * DM + h * HD;
#pragma unroll
        for (int jn = 0; jn < 4; ++jn)
          yp[jn * 16 + l16] = f2bf(o[mi][jn][r] * invr);
      }
    }
  }
#undef ISSUE
}

extern "C" void kernel_launch(void* const* d_in, const int* in_sizes, int n_in,
                              void* d_out, int out_size, void* d_ws, size_t ws_size,
                              hipStream_t stream) {
  const float* x     = (const float*)d_in[0];
  const float* Wqkv  = (const float*)d_in[1];
  const float* Wproj = (const float*)d_in[2];
  float* out = (float*)d_out;
  char* ws = (char*)d_ws;
  // ws layout (72 MiB):
  bf16_t* qkv = (bf16_t*)(ws);                 // 48 MiB (V third unused)
  bf16_t* Wt1 = (bf16_t*)(ws + 50331648);      // 6 MiB
  bf16_t* Wt2 = (bf16_t*)(ws + 56623104);      // 2 MiB
  bf16_t* xb  = (bf16_t*)(ws + 58720256);      // 16 MiB (dead after GEMM1)
  bf16_t* y   = xb;                            // attn output aliases xb
  // V^T parked in d_out's first 16 MiB; dead before GEMM2 overwrites d_out.
  bf16_t* vt  = (bf16_t*)d_out;

  k_transpose<<<dim3(QKV_W / 32, DM / 32), dim3(32, 8), 0, stream>>>(Wqkv, Wt1, DM, QKV_W);
  k_transpose<<<dim3(DM / 32, DM / 32), dim3(32, 8), 0, stream>>>(Wproj, Wt2, DM, DM);
  k_cvt<<<(BATCH * SEQ * DM) / (4 * 256), 256, 0, stream>>>(x, xb);
  k_gqkv<<<512, 512, 0, stream>>>(xb, Wt1, qkv, vt);
  k_rope<<<(BATCH * SEQ * NH * 32) / 256, 256, 0, stream>>>(qkv);
  k_attn<<<512, 256, 0, stream>>>(qkv, vt, y);
  k_gemm<0><<<dim3(DM / 128, (BATCH * SEQ) / 128), 256, 0, stream>>>(
      y, Wt2, out, nullptr, BATCH * SEQ, DM, DM);
}

// Round 6
// 251.112 us; speedup vs baseline: 1.0308x; 1.0046x over previous
//
#include <hip/hip_runtime.h>

// Causal self-attention fwd: x(4,2048,1024)fp32, W_qkv(1024,3072), W_proj(1024,1024)
// Pipeline (4 launches): [k_prep: W transposes + x->bf16] [GEMM1 qkv + fused
//   V-transpose + fused K-RoPE] [flash attn w/ fused Q-RoPE] [GEMM2 out]
// R5: attn 32q/wave, paired Q-tiles, exp2 shift-free softmax.
// R6: swapped QK^T + in-register P via cvt_pk_bf16 + permlane swaps (no P LDS).
// R9/R10 lessons: K-granule counted-vmcnt pipelines on this thin-K shape (16
//   K-tiles, 1 block/CU) land at ~750 TF regardless of conflicts (R10: 0
//   conflicts, 70.6us vs 2-phase 68.0us) -> GEMM1 reverted to proven 128^2
//   2-phase kernel.
// R11: launch consolidation 7->4: k_rope DELETED (K-RoPE fused into GEMM1
//   epilogue via shfl_xor(1) lane-pair + sincosf, Q-RoPE fused into attn's
//   Q-load where pairs are in-lane); transposes+cvt merged into k_prep.
//   Saves rope's 67MB qkv round-trip + 3 launch gaps; rope math now fp32
//   on fp32 accs (one less bf16 quantization).

#define BATCH 4
#define SEQ   2048
#define DM    1024
#define NH    16
#define HD    64
#define QKV_W 3072

typedef short bf16x8 __attribute__((ext_vector_type(8)));
typedef float f32x4  __attribute__((ext_vector_type(4)));
typedef unsigned u32x4 __attribute__((ext_vector_type(4)));
typedef unsigned short bf16_t;

#define NLT 0.28782313662425575f    // ln(10000)/32

__device__ __forceinline__ unsigned short f2bf(float f) {
  unsigned u = __float_as_uint(f);
  u += 0x7fffu + ((u >> 16) & 1u);   // round-to-nearest-even
  return (unsigned short)(u >> 16);
}
__device__ __forceinline__ float bf2f(unsigned short s) {
  return __uint_as_float((unsigned)s << 16);
}
// async global->LDS, 16B per lane; LDS dest is wave-uniform base + lane*16
__device__ __forceinline__ void gld16(const void* g, void* l) {
  __builtin_amdgcn_global_load_lds(
      (const __attribute__((address_space(1))) unsigned int*)g,
      (__attribute__((address_space(3))) unsigned int*)l, 16, 0, 0);
}
// packed f32x2 -> bf16x2 (RTNE), lo=a hi=b
__device__ __forceinline__ unsigned cvt_pk_bf16(float a, float b) {
  unsigned r;
  asm("v_cvt_pk_bf16_f32 %0, %1, %2" : "=v"(r) : "v"(a), "v"(b));
  return r;
}
// a.rows{2,3} <-> b.rows{0,1}  (rows = 16-lane groups)
__device__ __forceinline__ void permlane32_swap(unsigned& a, unsigned& b) {
  asm("v_permlane32_swap_b32 %0, %1" : "+v"(a), "+v"(b));
}
// a.rows{1,3} <-> b.rows{0,2}
__device__ __forceinline__ void permlane16_swap(unsigned& a, unsigned& b) {
  asm("v_permlane16_swap_b32 %0, %1" : "+v"(a), "+v"(b));
}

// ---------------- prep: both W transposes (fp32->bf16) + x->bf16 ------------
// blocks [0,3072): Wqkv transpose; [3072,4096): Wproj; [4096,12288): x cvt.
__global__ __launch_bounds__(256) void k_prep(const float* __restrict__ W1,
                                              const float* __restrict__ W2,
                                              const float* __restrict__ x,
                                              bf16_t* __restrict__ Wt1,
                                              bf16_t* __restrict__ Wt2,
                                              bf16_t* __restrict__ xb) {
  __shared__ float tile[32][33];
  const int blk = blockIdx.x, tid = threadIdx.x;
  if (blk < 4096) {
    const float* W;
    bf16_t* Wt;
    int N, bx, by;
    if (blk < 3072) { W = W1; Wt = Wt1; N = QKV_W; bx = blk % 96; by = blk / 96; }
    else            { W = W2; Wt = Wt2; N = DM;    bx = (blk - 3072) & 31; by = (blk - 3072) >> 5; }
    const int tx = tid & 31, ty = tid >> 5;   // (32,8)
    const int n0 = bx * 32, k0 = by * 32;
#pragma unroll
    for (int j = 0; j < 4; ++j)
      tile[ty + j * 8][tx] = W[(size_t)(k0 + ty + j * 8) * N + n0 + tx];
    __syncthreads();
#pragma unroll
    for (int j = 0; j < 4; ++j)
      Wt[(size_t)(n0 + ty + j * 8) * DM + k0 + tx] = f2bf(tile[tx][ty + j * 8]);
  } else {
    const int i = ((blk - 4096) * 256 + tid) * 4;
    float4 v = *(const float4*)(x + i);
    unsigned lo = (unsigned)f2bf(v.x) | ((unsigned)f2bf(v.y) << 16);
    unsigned hi = (unsigned)f2bf(v.z) | ((unsigned)f2bf(v.w) << 16);
    *(uint2*)(xb + i) = make_uint2(lo, hi);
  }
}

// ---------------- 128x128 bf16 GEMM (2-phase, proven 68us) ----------------
// MODE 0: fp32 C (GEMM2). MODE 1: qkv epilogue — cols<1024 (Q) raw bf16
// (RoPE applied in attn); cols in [1024,2048) (K) bf16 with FUSED RoPE
// (lane-pair via shfl_xor(1), wave-uniform branch since col%16 blocks of 16);
// cols>=2048 (V) -> vt[b][h][d][s] packed ushort4.
template<int MODE>
__global__ __launch_bounds__(256) void k_gemm(const bf16_t* __restrict__ A,
                                              const bf16_t* __restrict__ Bt,
                                              void* __restrict__ Cout,
                                              bf16_t* __restrict__ vt,
                                              int M, int N, int K) {
  __shared__ __align__(16) short As[128 * 64];
  __shared__ __align__(16) short Bs[128 * 64];
  const int tid = threadIdx.x;
  const int wave = tid >> 6, lane = tid & 63;
  const int quad = lane >> 4, l16 = lane & 15;
  const int wm = (wave >> 1) * 64, wn = (wave & 1) * 64;
  const int bm = blockIdx.y * 128, bn = blockIdx.x * 128;

  f32x4 acc[4][4];
#pragma unroll
  for (int i = 0; i < 4; ++i)
#pragma unroll
    for (int j = 0; j < 4; ++j) acc[i][j] = f32x4{0.f, 0.f, 0.f, 0.f};

  const int srow = tid >> 3;                       // 0..31
  const int sg   = (tid & 7) ^ (srow & 7);         // swizzled source granule
  const bf16_t* Ap = A  + (size_t)(bm + srow) * K + sg * 8;
  const bf16_t* Bp = Bt + (size_t)(bn + srow) * K + sg * 8;
  short* Ad = As + tid * 8;
  short* Bd = Bs + tid * 8;

  for (int k0 = 0; k0 < K; k0 += 64) {
    __syncthreads();
#pragma unroll
    for (int pp = 0; pp < 4; ++pp) {
      gld16(Ap + (size_t)(pp * 32) * K + k0, Ad + pp * 2048);
      gld16(Bp + (size_t)(pp * 32) * K + k0, Bd + pp * 2048);
    }
    __syncthreads();
#pragma unroll
    for (int ks = 0; ks < 2; ++ks) {
      bf16x8 af[4], bfr[4];
#pragma unroll
      for (int i = 0; i < 4; ++i)
        af[i] = *(const bf16x8*)&As[(wm + i * 16 + l16) * 64 +
                                    (((ks * 4 + quad) ^ (l16 & 7)) << 3)];
#pragma unroll
      for (int j = 0; j < 4; ++j)
        bfr[j] = *(const bf16x8*)&Bs[(wn + j * 16 + l16) * 64 +
                                     (((ks * 4 + quad) ^ (l16 & 7)) << 3)];
#pragma unroll
      for (int i = 0; i < 4; ++i)
#pragma unroll
        for (int j = 0; j < 4; ++j)
          acc[i][j] = __builtin_amdgcn_mfma_f32_16x16x32_bf16(af[i], bfr[j], acc[i][j], 0, 0, 0);
    }
  }
  // C row = quad*4+reg, col = l16 (verified mapping)
#pragma unroll
  for (int i = 0; i < 4; ++i)
#pragma unroll
    for (int j = 0; j < 4; ++j) {
      const int col = bn + wn + j * 16 + l16;
      const int row0 = bm + wm + i * 16 + quad * 4;
      if (MODE == 1 && col >= 2048) {
        const int d = col - 2048;
        const int hh = d >> 6, dd = d & 63;
        const int bb = row0 >> 11, ss = row0 & 2047;
        ushort4 pk;
        pk.x = f2bf(acc[i][j][0]); pk.y = f2bf(acc[i][j][1]);
        pk.z = f2bf(acc[i][j][2]); pk.w = f2bf(acc[i][j][3]);
        *(ushort4*)(vt + ((size_t)((bb * NH + hh) * HD + dd)) * SEQ + ss) = pk;
      } else if (MODE == 1 && col >= 1024) {
        // K columns: fused RoPE. freq idx from dim-within-head; pair = lane^1.
        const int ii = ((col - 1024) & 63) >> 1;
        const float inv = __expf((float)ii * -NLT);
        const float sgn = (col & 1) ? 1.0f : -1.0f;
#pragma unroll
        for (int r = 0; r < 4; ++r) {
          const float v = acc[i][j][r];
          const float p = __shfl_xor(v, 1, 64);
          float sn, cs;
          __sincosf((float)((row0 + r) & 2047) * inv, &sn, &cs);
          ((bf16_t*)Cout)[(size_t)(row0 + r) * N + col] = f2bf(v * cs + sgn * p * sn);
        }
      } else {
#pragma unroll
        for (int r = 0; r < 4; ++r) {
          if (MODE == 1)
            ((bf16_t*)Cout)[(size_t)(row0 + r) * N + col] = f2bf(acc[i][j][r]);
          else
            ((float*)Cout)[(size_t)(row0 + r) * N + col] = acc[i][j][r];
        }
      }
    }
}

// ---------------- flash attention ----------------
// 512 blocks, XCD-swizzled. Block: 128 Q-rows (4 waves x 32q), Q-tiles (p,15-p)
// => uniform 34 KV-iters. KV dbuf + cross-iter prefetch, 1 barrier/iter.
// Q pre-scaled by 0.125*log2e => p = exp2(s'), shift-free (cancels in norm).
// Q-RoPE FUSED here (GEMM1 writes raw Q): pairs are in-lane within bf16x8.
// Swapped QK^T: S^T = mfma(K, Q) so each lane holds P[q=l16][k=jn*16+quad*4+r];
// PV A-frags built in-register via cvt_pk + permlane32/16 swaps — no P LDS.
#define QSCALE 0.18033688011112042f   // 0.125 * log2(e)
__global__ __launch_bounds__(256, 2) void k_attn(const bf16_t* __restrict__ qkv,
                                                 const bf16_t* __restrict__ vt,
                                                 bf16_t* __restrict__ y) {
  __shared__ __align__(16) short KV[2][4][64 * 32];  // [buf][K0,K1,V0,V1]
  const int tid = threadIdx.x;
  const int lane = tid & 63;
  const int quad = lane >> 4, l16 = lane & 15;
  const int wave = tid >> 6;
  const int l = blockIdx.x;
  const int p = (l >> 3) & 7;                    // pair index 0..7
  const int g = ((l >> 6) << 3) | (l & 7);       // (h,b) group, const per XCD slice
  const int h = g & 15, b = g >> 4;
  const size_t bbase = (size_t)b * SEQ * QKV_W;
  const int srow = tid >> 2;            // staging row 0..63
  const int sc8  = (tid & 3) * 8;       // staging col 0,8,16,24
  const bf16_t* kbase = qkv + bbase + (size_t)srow * QKV_W + DM + h * HD + sc8;
  const bf16_t* vbase = vt + ((size_t)(b * NH + h) * HD + srow) * SEQ + sc8;

#define ISSUE(kv0, buf)                                              \
  do {                                                               \
    gld16(kbase + (size_t)(kv0) * QKV_W,      &KV[buf][0][tid * 8]); \
    gld16(kbase + (size_t)(kv0) * QKV_W + 32, &KV[buf][1][tid * 8]); \
    gld16(vbase + (kv0),                      &KV[buf][2][tid * 8]); \
    gld16(vbase + (kv0) + 32,                 &KV[buf][3][tid * 8]); \
  } while (0)

  int bufp = 0;
  ISSUE(0, 0);
  for (int half = 0; half < 2; ++half) {
    const int qt = half ? (15 - p) : p;
    const int qb = qt * 128 + wave * 32;         // wave's first q row
    // load Q fragments; apply RoPE (in-lane pairs) + QSCALE in fp32
    bf16x8 aq[2][2];
#pragma unroll
    for (int mi = 0; mi < 2; ++mi) {
      const float s_pos = (float)(qb + mi * 16 + l16);
#pragma unroll
      for (int kk = 0; kk < 2; ++kk) {
        const bf16_t* qp = qkv + bbase + (size_t)(qb + mi * 16 + l16) * QKV_W +
                           h * HD + kk * 32 + quad * 8;
        bf16x8 raw = *(const bf16x8*)qp;
        bf16x8 sc;
#pragma unroll
        for (int t = 0; t < 4; ++t) {
          const int ii = kk * 16 + quad * 4 + t;
          const float inv = __expf((float)ii * -NLT);
          float sn, cs;
          __sincosf(s_pos * inv, &sn, &cs);
          const float e = bf2f((unsigned short)raw[2 * t]);
          const float o = bf2f((unsigned short)raw[2 * t + 1]);
          sc[2 * t]     = (short)f2bf((e * cs - o * sn) * QSCALE);
          sc[2 * t + 1] = (short)f2bf((e * sn + o * cs) * QSCALE);
        }
        aq[mi][kk] = sc;
      }
    }
    f32x4 o[2][4];
    float lsum[2];
#pragma unroll
    for (int mi = 0; mi < 2; ++mi) {
      lsum[mi] = 0.f;
#pragma unroll
      for (int jn = 0; jn < 4; ++jn) o[mi][jn] = f32x4{0.f, 0.f, 0.f, 0.f};
    }
    const int qr0 = qb + l16;                    // this lane's q row (mi=0)

    const int jmax = 2 * qt + 1;
    for (int j = 0; j <= jmax; ++j) {
      const int kv0 = j * 64;
      __syncthreads();   // drains this buf's loads; WAR-protects prefetch target
      if (j < jmax)          ISSUE(kv0 + 64, bufp ^ 1);
      else if (half == 0)    ISSUE(0, bufp ^ 1);
      if (kv0 <= qb + 31) {  // else: fully masked for this wave — skip
        const bool needmask = (kv0 + 63 > qb);
        const short* Kc0 = &KV[bufp][0][0];
        const short* Kc1 = &KV[bufp][1][0];
        const short* Vc0 = &KV[bufp][2][0];
        const short* Vc1 = &KV[bufp][3][0];

        // S^T frags: st[jn][mi]; row = kv (jn*16+quad*4+r), col = q (mi*16+l16)
        f32x4 st[4][2];
#pragma unroll
        for (int jn = 0; jn < 4; ++jn) {
          bf16x8 ak0 = *(const bf16x8*)&Kc0[(jn * 16 + l16) * 32 + quad * 8];
          bf16x8 ak1 = *(const bf16x8*)&Kc1[(jn * 16 + l16) * 32 + quad * 8];
#pragma unroll
          for (int mi = 0; mi < 2; ++mi) {
            f32x4 s4 = f32x4{0.f, 0.f, 0.f, 0.f};
            s4 = __builtin_amdgcn_mfma_f32_16x16x32_bf16(ak0, aq[mi][0], s4, 0, 0, 0);
            s4 = __builtin_amdgcn_mfma_f32_16x16x32_bf16(ak1, aq[mi][1], s4, 0, 0, 0);
            st[jn][mi] = s4;
          }
        }
        // p = exp2(s'); mask near diagonal; pack r-pairs to bf16x2
        unsigned pk[4][2][2];
#pragma unroll
        for (int jn = 0; jn < 4; ++jn)
#pragma unroll
          for (int mi = 0; mi < 2; ++mi) {
            const int kvb = kv0 + jn * 16 + quad * 4;
            const int qr = qr0 + mi * 16;
            float e[4];
#pragma unroll
            for (int r = 0; r < 4; ++r) {
              float v = __builtin_amdgcn_exp2f(st[jn][mi][r]);
              if (needmask) v = (kvb + r <= qr) ? v : 0.f;
              lsum[mi] += v;
              e[r] = v;
            }
            pk[jn][mi][0] = cvt_pk_bf16(e[0], e[1]);
            pk[jn][mi][1] = cvt_pk_bf16(e[2], e[3]);
          }
        // redistribute across quads -> PV A-frags ap[mi][ks]
        bf16x8 ap[2][2];
#pragma unroll
        for (int mi = 0; mi < 2; ++mi)
#pragma unroll
          for (int ks = 0; ks < 2; ++ks) {
            unsigned a0 = pk[2 * ks][mi][0], b0 = pk[2 * ks + 1][mi][0];
            permlane32_swap(a0, b0);
            permlane16_swap(a0, b0);
            unsigned a1 = pk[2 * ks][mi][1], b1 = pk[2 * ks + 1][mi][1];
            permlane32_swap(a1, b1);
            permlane16_swap(a1, b1);
            union { u32x4 u; bf16x8 s; } f;
            f.u = (u32x4){a0, a1, b0, b1};
            ap[mi][ks] = f.s;
          }
        // O += P V  (V frags shared across mi)
#pragma unroll
        for (int ks = 0; ks < 2; ++ks) {
          const short* Vc = ks ? Vc1 : Vc0;
#pragma unroll
          for (int jn = 0; jn < 4; ++jn) {
            bf16x8 bv = *(const bf16x8*)&Vc[(jn * 16 + l16) * 32 + quad * 8];
            o[0][jn] = __builtin_amdgcn_mfma_f32_16x16x32_bf16(ap[0][ks], bv, o[0][jn], 0, 0, 0);
            o[1][jn] = __builtin_amdgcn_mfma_f32_16x16x32_bf16(ap[1][ks], bv, o[1][jn], 0, 0, 0);
          }
        }
      }
      bufp ^= 1;
    }
    // normalize + write: lane holds full row-sum for q = l16 (+mi*16) after
    // quad-reduce; redistribute inv to output rows (quad*4+r) via shfl.
#pragma unroll
    for (int mi = 0; mi < 2; ++mi) {
      float s = lsum[mi];
      s += __shfl_xor(s, 16, 64);
      s += __shfl_xor(s, 32, 64);
      const float inv = 1.0f / s;
#pragma unroll
      for (int r = 0; r < 4; ++r) {
        const float invr = __shfl(inv, quad * 4 + r, 64);
        const int qr = qb + mi * 16 + quad * 4 + r;
        bf16_t* yp = y + ((size_t)b * SEQ + qr) * DM + h * HD;
#pragma unroll
        for (int jn = 0; jn < 4; ++jn)
          yp[jn * 16 + l16] = f2bf(o[mi][jn][r] * invr);
      }
    }
  }
#undef ISSUE
}

extern "C" void kernel_launch(void* const* d_in, const int* in_sizes, int n_in,
                              void* d_out, int out_size, void* d_ws, size_t ws_size,
                              hipStream_t stream) {
  const float* x     = (const float*)d_in[0];
  const float* Wqkv  = (const float*)d_in[1];
  const float* Wproj = (const float*)d_in[2];
  float* out = (float*)d_out;
  char* ws = (char*)d_ws;
  // ws layout (72 MiB):
  bf16_t* qkv = (bf16_t*)(ws);                 // 48 MiB (V third unused)
  bf16_t* Wt1 = (bf16_t*)(ws + 50331648);      // 6 MiB
  bf16_t* Wt2 = (bf16_t*)(ws + 56623104);      // 2 MiB
  bf16_t* xb  = (bf16_t*)(ws + 58720256);      // 16 MiB (dead after GEMM1)
  bf16_t* y   = xb;                            // attn output aliases xb
  // V^T parked in d_out's first 16 MiB; dead before GEMM2 overwrites d_out.
  bf16_t* vt  = (bf16_t*)d_out;

  k_prep<<<12288, 256, 0, stream>>>(Wqkv, Wproj, x, Wt1, Wt2, xb);
  k_gemm<1><<<dim3(QKV_W / 128, (BATCH * SEQ) / 128), 256, 0, stream>>>(
      xb, Wt1, qkv, vt, BATCH * SEQ, QKV_W, DM);
  k_attn<<<512, 256, 0, stream>>>(qkv, vt, y);
  k_gemm<0><<<dim3(DM / 128, (BATCH * SEQ) / 128), 256, 0, stream>>>(
      y, Wt2, out, nullptr, BATCH * SEQ, DM, DM);
}